// Round 5
// baseline (94.212 us; speedup 1.0000x reference)
//
#include <hip/hip_runtime.h>
#include <stdint.h>

#define N 8192
#define MAX_E (64 * N)          // 524288
#define NCHUNK (N / 64)         // 128 mask chunks per row
#define TILE 1024               // cols per block (16KB LDS)
#define CTILES (N / TILE)       // 8 col-tiles
#define ROWS_PER_WAVE 4
#define WAVES 4
#define ROWS_PER_BLOCK (ROWS_PER_WAVE * WAVES)  // 16
#define RGROUPS (N / ROWS_PER_BLOCK)            // 512

// Exact replication of numpy f32: sum(pos*pos, -1) = ((x*x)+(y*y))+(z*z),
// each product rounded (no fma).
__device__ __forceinline__ float sq_exact(float x, float y, float z) {
    return __fadd_rn(__fadd_rn(__fmul_rn(x, x), __fmul_rn(y, y)), __fmul_rn(z, z));
}

// d2 = RN(sqsum - RN(2*dot)); 2*dot is exact so fma(-2,dot,sqsum) is bit-identical.
// dist<5 <=> d2 < 0x1.8ffffep+4f (largest f32 below 25 has correctly-rounded sqrt
// equal to exactly 5.0, so that value must be excluded).
__device__ __forceinline__ bool edge_pred(float xi, float yi, float zi, float sqi,
                                          const float4& pj) {
    float dot = __fmaf_rn(zi, pj.z, __fmaf_rn(yi, pj.y, __fmul_rn(xi, pj.x)));
    float d2  = __fmaf_rn(-2.0f, dot, __fadd_rn(sqi, pj.w));
    return d2 < 0x1.8ffffep+4f;
}

// Pass 1: 2D grid (row-group, col-tile). Each wave: 4 rows x 1024 cols.
// Ballot masks kept in owner-lane registers (lanes 0..7 hold chunk-pairs 0..7
// of this tile), flushed once at the end. Partial counts per (row, tile).
__global__ __launch_bounds__(256) void mask_kernel(const float* __restrict__ posf,
                                                   uint64_t* __restrict__ masks,
                                                   int* __restrict__ counts8) {
    __shared__ float4 pts[TILE];
    const int tid  = threadIdx.x;
    const int wave = tid >> 6;
    const int lane = tid & 63;
    const int row0 = blockIdx.x * ROWS_PER_BLOCK + wave * ROWS_PER_WAVE;
    const int ct   = blockIdx.y;          // col tile
    const int cb   = ct * TILE;           // col base

    float xi[ROWS_PER_WAVE], yi[ROWS_PER_WAVE], zi[ROWS_PER_WAVE], sqi[ROWS_PER_WAVE];
    uint64_t k0[ROWS_PER_WAVE], k1[ROWS_PER_WAVE];
#pragma unroll
    for (int r = 0; r < ROWS_PER_WAVE; r++) {
        int i = row0 + r;
        xi[r] = posf[3 * i + 0];
        yi[r] = posf[3 * i + 1];
        zi[r] = posf[3 * i + 2];
        sqi[r] = sq_exact(xi[r], yi[r], zi[r]);
        k0[r] = 0; k1[r] = 0;
    }

    for (int k = tid; k < TILE; k += 256) {
        float x = posf[3 * (cb + k) + 0];
        float y = posf[3 * (cb + k) + 1];
        float z = posf[3 * (cb + k) + 2];
        pts[k] = make_float4(x, y, z, sq_exact(x, y, z));
    }
    __syncthreads();

#pragma unroll
    for (int c = 0; c < TILE; c += 128) {
        const int owner = c >> 7;         // 0..7, wave-uniform
        float4 pa = pts[c + lane];
        float4 pb = pts[c + 64 + lane];
#pragma unroll
        for (int r = 0; r < ROWS_PER_WAVE; r++) {
            uint64_t ma = __ballot(edge_pred(xi[r], yi[r], zi[r], sqi[r], pa));
            if (lane == owner) k0[r] = ma;
            uint64_t mb = __ballot(edge_pred(xi[r], yi[r], zi[r], sqi[r], pb));
            if (lane == owner) k1[r] = mb;
        }
    }

#pragma unroll
    for (int r = 0; r < ROWS_PER_WAVE; r++) {
        const int row = row0 + r;
        // clear the self bit if this tile contains column `row`
        if ((row >> 10) == ct) {
            const int ls = (row & (TILE - 1)) >> 6;   // local chunk 0..15
            if (lane == (ls >> 1)) {
                uint64_t clr = ~(1ull << (row & 63));
                if (ls & 1) k1[r] &= clr; else k0[r] &= clr;
            }
        }
        if (lane < CTILES) {   // lanes 0..7 hold chunk-pairs
            ulonglong2 v; v.x = k0[r]; v.y = k1[r];
            ((ulonglong2*)(masks + (size_t)row * NCHUNK))[ct * (TILE / 128) + lane] = v;
        }
        int t = __popcll(k0[r]) + __popcll(k1[r]);
#pragma unroll
        for (int o = 32; o > 0; o >>= 1) t += __shfl_down(t, o);
        if (lane == 0) counts8[row * CTILES + ct] = t;
    }
}

__global__ __launch_bounds__(256) void scan_kernel(const int* __restrict__ counts8,
                                                   int* __restrict__ offsets) {
    __shared__ int part[256];
    const int t = threadIdx.x;
    int local[32];
    int s = 0;
#pragma unroll
    for (int k = 0; k < 32; k++) {
        int v = 0;
#pragma unroll
        for (int j = 0; j < CTILES; j++) v += counts8[(t * 32 + k) * CTILES + j];
        local[k] = v; s += v;
    }
    part[t] = s;
    __syncthreads();
    for (int off = 1; off < 256; off <<= 1) {
        int v = (t >= off) ? part[t - off] : 0;
        __syncthreads();
        part[t] += v;
        __syncthreads();
    }
    int run = (t > 0) ? part[t - 1] : 0;  // exclusive base
#pragma unroll
    for (int k = 0; k < 32; k++) { offsets[t * 32 + k] = run; run += local[k]; }
    if (t == 255) offsets[N] = part[255];  // total edge count
}

// Pass 2: masks -> ordered edge list + tail fill with -1.
// One wave per row; lane l holds chunks 2l,2l+1; wave-exclusive-scan of
// popcounts gives in-order slots.
__global__ __launch_bounds__(256) void emit_kernel(const uint64_t* __restrict__ masks,
                                                   const int* __restrict__ offsets,
                                                   int* __restrict__ out) {
    const int wave = threadIdx.x >> 6;
    const int lane = threadIdx.x & 63;
    const int row  = blockIdx.x * 4 + wave;

    // tail fill: slots [E, MAX_E) of both halves get -1. 524288 threads cover
    // the <=262K tail slots with one conditional store pair each.
    {
        const int E = offsets[N];
        const int idx = E + blockIdx.x * 256 + threadIdx.x;
        if (idx < MAX_E) { out[idx] = -1; out[MAX_E + idx] = -1; }
    }

    ulonglong2 v = ((const ulonglong2*)(masks + (size_t)row * NCHUNK))[lane];
    int s0 = __popcll(v.x), s1 = __popcll(v.y);
    int x = s0 + s1;
#pragma unroll
    for (int o = 1; o < 64; o <<= 1) {
        int t = __shfl_up(x, o);
        if (lane >= o) x += t;
    }
    int slot = offsets[row] + (x - (s0 + s1));  // exclusive prefix within row

    const int col0 = lane * 128;  // chunk 2*lane covers cols [128*lane, 128*lane+64)
    uint64_t m = v.x;
    while (m) {
        int b = __ffsll((unsigned long long)m) - 1;
        m &= m - 1;
        if (slot < MAX_E) { out[slot] = row; out[MAX_E + slot] = col0 + b; }
        slot++;
    }
    m = v.y;
    while (m) {
        int b = __ffsll((unsigned long long)m) - 1;
        m &= m - 1;
        if (slot < MAX_E) { out[slot] = row; out[MAX_E + slot] = col0 + 64 + b; }
        slot++;
    }
}

extern "C" void kernel_launch(void* const* d_in, const int* in_sizes, int n_in,
                              void* d_out, int out_size, void* d_ws, size_t ws_size,
                              hipStream_t stream) {
    const float* posf = (const float*)d_in[0];
    int* out = (int*)d_out;
    int* counts8 = (int*)d_ws;                                   // 8*N ints = 256KB
    int* offsets = (int*)((char*)d_ws + (256 << 10));            // N+1 ints
    uint64_t* masks = (uint64_t*)((char*)d_ws + (512 << 10));    // 8 MB

    dim3 grid(RGROUPS, CTILES);
    mask_kernel<<<grid, 256, 0, stream>>>(posf, masks, counts8);
    scan_kernel<<<1, 256, 0, stream>>>(counts8, offsets);
    emit_kernel<<<N / 4, 256, 0, stream>>>(masks, offsets, out);
}

// Round 6
// 87.427 us; speedup vs baseline: 1.0776x; 1.0776x over previous
//
#include <hip/hip_runtime.h>
#include <stdint.h>

#define N 8192
#define MAX_E (64 * N)          // 524288
#define NCHUNK (N / 64)         // 128 mask chunks per row
#define TILE 2048               // cols per block (32KB LDS)
#define CTILES (N / TILE)       // 4 col-tiles
#define CPAIRS (TILE / 128)     // 16 chunk-pairs per tile
#define ROWS_PER_WAVE 8
#define WAVES 4
#define ROWS_PER_BLOCK (ROWS_PER_WAVE * WAVES)  // 32
#define RGROUPS (N / ROWS_PER_BLOCK)            // 256

// Exact replication of numpy f32: sum(pos*pos, -1) = ((x*x)+(y*y))+(z*z),
// each product rounded (no fma).
__device__ __forceinline__ float sq_exact(float x, float y, float z) {
    return __fadd_rn(__fadd_rn(__fmul_rn(x, x), __fmul_rn(y, y)), __fmul_rn(z, z));
}

// d2 = RN(sqsum - RN(2*dot)); 2*dot is exact so fma(-2,dot,sqsum) is bit-identical.
// dist<5 <=> d2 < 0x1.8ffffep+4f (largest f32 below 25 has correctly-rounded sqrt
// equal to exactly 5.0, so that value must be excluded).
__device__ __forceinline__ bool edge_pred(float xi, float yi, float zi, float sqi,
                                          const float4& pj) {
    float dot = __fmaf_rn(zi, pj.z, __fmaf_rn(yi, pj.y, __fmul_rn(xi, pj.x)));
    float d2  = __fmaf_rn(-2.0f, dot, __fadd_rn(sqi, pj.w));
    return d2 < 0x1.8ffffep+4f;
}

// Pass 1: grid (row-group, col-tile). Each wave: 8 rows x 2048 cols.
// 2 ds_read_b128 feed 16 ballots; next chunk's points prefetched before the
// ballot body so LDS latency overlaps VALU. Ballot masks kept in owner-lane
// registers (lanes 0..15 hold this tile's 16 chunk-pairs), flushed once.
__global__ __launch_bounds__(256) void mask_kernel(const float* __restrict__ posf,
                                                   uint64_t* __restrict__ masks,
                                                   int* __restrict__ counts4) {
    __shared__ float4 pts[TILE];
    const int tid  = threadIdx.x;
    const int wave = tid >> 6;
    const int lane = tid & 63;
    const int row0 = blockIdx.x * ROWS_PER_BLOCK + wave * ROWS_PER_WAVE;
    const int ct   = blockIdx.y;          // col tile
    const int cb   = ct * TILE;           // col base

    float xi[ROWS_PER_WAVE], yi[ROWS_PER_WAVE], zi[ROWS_PER_WAVE], sqi[ROWS_PER_WAVE];
    uint64_t k0[ROWS_PER_WAVE], k1[ROWS_PER_WAVE];
#pragma unroll
    for (int r = 0; r < ROWS_PER_WAVE; r++) {
        int i = row0 + r;
        xi[r] = posf[3 * i + 0];
        yi[r] = posf[3 * i + 1];
        zi[r] = posf[3 * i + 2];
        sqi[r] = sq_exact(xi[r], yi[r], zi[r]);
        k0[r] = 0; k1[r] = 0;
    }

    for (int k = tid; k < TILE; k += 256) {
        float x = posf[3 * (cb + k) + 0];
        float y = posf[3 * (cb + k) + 1];
        float z = posf[3 * (cb + k) + 2];
        pts[k] = make_float4(x, y, z, sq_exact(x, y, z));
    }
    __syncthreads();

    float4 pa = pts[lane];
    float4 pb = pts[64 + lane];
#pragma unroll
    for (int c = 0; c < TILE; c += 128) {
        // prefetch next chunk-pair (masked index: always in-bounds, no branch)
        float4 na = pts[((c + 128) & (TILE - 1)) + lane];
        float4 nb = pts[((c + 192) & (TILE - 1)) + lane];
        const int owner = c >> 7;         // 0..15, wave-uniform
#pragma unroll
        for (int r = 0; r < ROWS_PER_WAVE; r++) {
            uint64_t ma = __ballot(edge_pred(xi[r], yi[r], zi[r], sqi[r], pa));
            if (lane == owner) k0[r] = ma;
            uint64_t mb = __ballot(edge_pred(xi[r], yi[r], zi[r], sqi[r], pb));
            if (lane == owner) k1[r] = mb;
        }
        pa = na; pb = nb;
    }

#pragma unroll
    for (int r = 0; r < ROWS_PER_WAVE; r++) {
        const int row = row0 + r;
        // clear the self bit if this tile contains column `row`
        if ((row >> 11) == ct) {
            const int ls = (row & (TILE - 1)) >> 6;   // local chunk 0..31
            if (lane == (ls >> 1)) {
                uint64_t clr = ~(1ull << (row & 63));
                if (ls & 1) k1[r] &= clr; else k0[r] &= clr;
            }
        }
        if (lane < CPAIRS) {   // lanes 0..15 hold this tile's chunk-pairs
            ulonglong2 v; v.x = k0[r]; v.y = k1[r];
            ((ulonglong2*)(masks + (size_t)row * NCHUNK))[ct * CPAIRS + lane] = v;
        }
        int t = __popcll(k0[r]) + __popcll(k1[r]);
#pragma unroll
        for (int o = 32; o > 0; o >>= 1) t += __shfl_down(t, o);
        if (lane == 0) counts4[row * CTILES + ct] = t;
    }
}

__global__ __launch_bounds__(256) void scan_kernel(const int* __restrict__ counts4,
                                                   int* __restrict__ offsets) {
    __shared__ int part[256];
    const int t = threadIdx.x;
    int local[32];
    int s = 0;
#pragma unroll
    for (int k = 0; k < 32; k++) {
        int v = 0;
#pragma unroll
        for (int j = 0; j < CTILES; j++) v += counts4[(t * 32 + k) * CTILES + j];
        local[k] = v; s += v;
    }
    part[t] = s;
    __syncthreads();
    for (int off = 1; off < 256; off <<= 1) {
        int v = (t >= off) ? part[t - off] : 0;
        __syncthreads();
        part[t] += v;
        __syncthreads();
    }
    int run = (t > 0) ? part[t - 1] : 0;  // exclusive base
#pragma unroll
    for (int k = 0; k < 32; k++) { offsets[t * 32 + k] = run; run += local[k]; }
    if (t == 255) offsets[N] = part[255];  // total edge count
}

// Pass 2: masks -> ordered edge list + tail fill with -1.
// One wave per row; lane l holds chunks 2l,2l+1; wave-exclusive-scan of
// popcounts gives in-order slots.
__global__ __launch_bounds__(256) void emit_kernel(const uint64_t* __restrict__ masks,
                                                   const int* __restrict__ offsets,
                                                   int* __restrict__ out) {
    const int wave = threadIdx.x >> 6;
    const int lane = threadIdx.x & 63;
    const int row  = blockIdx.x * 4 + wave;

    // tail fill: slots [E, MAX_E) of both halves get -1. 524288 threads cover
    // the <=262K tail slots with one conditional store pair each.
    {
        const int E = offsets[N];
        const int idx = E + blockIdx.x * 256 + threadIdx.x;
        if (idx < MAX_E) { out[idx] = -1; out[MAX_E + idx] = -1; }
    }

    ulonglong2 v = ((const ulonglong2*)(masks + (size_t)row * NCHUNK))[lane];
    int s0 = __popcll(v.x), s1 = __popcll(v.y);
    int x = s0 + s1;
#pragma unroll
    for (int o = 1; o < 64; o <<= 1) {
        int t = __shfl_up(x, o);
        if (lane >= o) x += t;
    }
    int slot = offsets[row] + (x - (s0 + s1));  // exclusive prefix within row

    const int col0 = lane * 128;  // chunk 2*lane covers cols [128*lane, 128*lane+64)
    uint64_t m = v.x;
    while (m) {
        int b = __ffsll((unsigned long long)m) - 1;
        m &= m - 1;
        if (slot < MAX_E) { out[slot] = row; out[MAX_E + slot] = col0 + b; }
        slot++;
    }
    m = v.y;
    while (m) {
        int b = __ffsll((unsigned long long)m) - 1;
        m &= m - 1;
        if (slot < MAX_E) { out[slot] = row; out[MAX_E + slot] = col0 + 64 + b; }
        slot++;
    }
}

extern "C" void kernel_launch(void* const* d_in, const int* in_sizes, int n_in,
                              void* d_out, int out_size, void* d_ws, size_t ws_size,
                              hipStream_t stream) {
    const float* posf = (const float*)d_in[0];
    int* out = (int*)d_out;
    int* counts4 = (int*)d_ws;                                   // 4*N ints = 128KB
    int* offsets = (int*)((char*)d_ws + (256 << 10));            // N+1 ints
    uint64_t* masks = (uint64_t*)((char*)d_ws + (512 << 10));    // 8 MB

    dim3 grid(RGROUPS, CTILES);
    mask_kernel<<<grid, 256, 0, stream>>>(posf, masks, counts4);
    scan_kernel<<<1, 256, 0, stream>>>(counts4, offsets);
    emit_kernel<<<N / 4, 256, 0, stream>>>(masks, offsets, out);
}